// Round 1
// baseline (186.216 us; speedup 1.0000x reference)
//
#include <hip/hip_runtime.h>
#include <hip/hip_bf16.h>
#include <math.h>

#define BB 8
#define NN 512
#define DD 256
#define BNT 4096   // B*N

typedef __attribute__((ext_vector_type(8))) short short8;
typedef __attribute__((ext_vector_type(4))) float f32x4;

// Workspace layout (float offsets). ~18 MB.
#define OFF_S0B   0u          // bf16 [4096][256]      s0 row-major
#define OFF_TT    524288u     // bf16 [8][256][3072]   TT[b][e][r*512+i] = T_r[i][e]+relb_r[e]
#define OFF_WCT   6815744u    // bf16 [256][1536]      WcT[e][r*256+d] = relW[r][d][e]
#define OFF_WBT   7012352u    // bf16 [1024][256]      Wbig^T (c rows, k=d)
#define OFF_BB    7143424u    // fp32 [1024]           h1b|outb
#define OFF_REL   7144448u    // u8   [8][512][512]    relation codes (self=6)

// d_out layout (floats)
#define OUT0_OFF   0u        // output  [8][512][256]
#define INTERP_OFF 1048576u  // interp  [3][4096]
#define SYM_OFF    1060864u  // symbols [8][512][256]

__device__ __forceinline__ float gelu_exact(float x) {
    return 0.5f * x * (1.0f + erff(x * 0.70710678118654752f));
}

__device__ __forceinline__ ushort f2bf(float x) {
    __hip_bfloat16 h = __float2bfloat16(x);
    union { __hip_bfloat16 b; ushort u; } cv;
    cv.b = h;
    return cv.u;
}

// Branch-free classification (reference if/elif priority, applied in reverse).
__device__ __forceinline__ int rel_of(float dx, float dy) {
    int r = (fabsf(dx) < 0.3f && fabsf(dy) < 0.3f) ? 4 : 5;
    r = (dx >  0.5f) ? 3 : r;
    r = (dx < -0.5f) ? 2 : r;
    r = (dy < -0.5f) ? 1 : r;
    r = (dy >  0.5f) ? 0 : r;
    return r;
}

// Pack 8 fp32 -> bf16x8 fragment.
__device__ __forceinline__ short8 pack_bf8(float4 x, float4 y) {
    union { ushort u[8]; short8 v; } o;
    o.u[0] = f2bf(x.x); o.u[1] = f2bf(x.y); o.u[2] = f2bf(x.z); o.u[3] = f2bf(x.w);
    o.u[4] = f2bf(y.x); o.u[5] = f2bf(y.y); o.u[6] = f2bf(y.z); o.u[7] = f2bf(y.w);
    return o.v;
}

// One-hot bf16 fragment from 8 relation-code bytes: 1.0 where code==rr.
__device__ __forceinline__ short8 onehot8(uint2 cw, unsigned rr) {
    union { ushort u[8]; short8 v; } o;
    unsigned m = rr * 0x01010101u;
    unsigned x = cw.x ^ m, y = cw.y ^ m;
#pragma unroll
    for (int t = 0; t < 4; t++) {
        o.u[t]     = (((x >> (8 * t)) & 255u) == 0u) ? 0x3F80 : 0;
        o.u[t + 4] = (((y >> (8 * t)) & 255u) == 0u) ? 0x3F80 : 0;
    }
    return o.v;
}

// 64x64 tile, 4 waves (2x2). Fragment layout (m89/m91 verified):
// A: m=lane&15, k=quad*8+j; B: n=lane&15, k=quad*8+j;
// C/D: col=lane&15, row=quad*4+reg.
#define WAVE_IDS()                                             \
    const int lane = tid & 63, w = tid >> 6;                   \
    const int wm = w >> 1, wn = w & 1;                         \
    const int quad = lane >> 4, l15 = lane & 15;

#define ACC_INIT()                                             \
    f32x4 acc[2][2];                                           \
    _Pragma("unroll") for (int mt = 0; mt < 2; mt++)           \
    _Pragma("unroll") for (int nt = 0; nt < 2; nt++)           \
        acc[mt][nt] = (f32x4){0.f, 0.f, 0.f, 0.f};

#define MFMA4(a0, a1, b0, b1)                                                     \
    acc[0][0] = __builtin_amdgcn_mfma_f32_16x16x32_bf16(a0, b0, acc[0][0], 0, 0, 0); \
    acc[0][1] = __builtin_amdgcn_mfma_f32_16x16x32_bf16(a0, b1, acc[0][1], 0, 0, 0); \
    acc[1][0] = __builtin_amdgcn_mfma_f32_16x16x32_bf16(a1, b0, acc[1][0], 0, 0, 0); \
    acc[1][1] = __builtin_amdgcn_mfma_f32_16x16x32_bf16(a1, b1, acc[1][1], 0, 0, 0);

// ---------------------------------------------------------------- front ---
// Fused prep (blocks 0..1535) + gather (1536..2559, 4 rows/block, float4)
// + classify (2560..3071).
__global__ __launch_bounds__(256) void front_kernel(
    const int* __restrict__ ids, const float* __restrict__ positions,
    const float* __restrict__ symt, const float* __restrict__ layt,
    const float* __restrict__ relW, const float* __restrict__ h1W,
    const float* __restrict__ outW, const float* __restrict__ h1b,
    const float* __restrict__ outb, const float* __restrict__ h2b,
    ushort* __restrict__ WcT, ushort* __restrict__ WbT,
    float* __restrict__ bbig, float* __restrict__ outI,
    float* __restrict__ symOut, ushort* __restrict__ s0b,
    unsigned char* __restrict__ rel)
{
    __shared__ float px[NN], py[NN];
    int blk = blockIdx.x, tid = threadIdx.x;
    if (blk < 1536) {
        int idx = blk * 256 + tid;               // 393216
        {
            int e = idx / 1536, k = idx - e * 1536;
            int r = k >> 8, d = k & 255;
            WcT[idx] = f2bf(relW[(r * DD + d) * DD + e]);
        }
        if (idx < 262144) {
            int c = idx >> 8, d = idx & 255;
            float v;
            if (c < 768) { int r = c >> 8, e = c & 255; v = h1W[(r * DD + d) * DD + e]; }
            else         { v = outW[d * DD + (c - 768)]; }
            WbT[idx] = f2bf(v);
        }
        if (idx < 3 * BNT) outI[idx] = h2b[idx >> 12];
        if (idx < 1024) bbig[idx] = (idx < 768) ? h1b[idx] : outb[idx - 768];
    } else if (blk < 2560) {
        int row = (blk - 1536) * 4 + (tid >> 6); // 4 rows/block
        int d = (tid & 63) * 4;
        int id = ids[row];
        float4 a = *(const float4*)&symt[(size_t)id * DD + d];
        float4 c = *(const float4*)&layt[(size_t)id * DD + d];
        float4 v = {a.x + c.x, a.y + c.y, a.z + c.z, a.w + c.w};
        *(float4*)&symOut[(size_t)row * DD + d] = v;
        union { ushort u[4]; uint2 q; } p;
        p.u[0] = f2bf(v.x); p.u[1] = f2bf(v.y); p.u[2] = f2bf(v.z); p.u[3] = f2bf(v.w);
        *(uint2*)&s0b[(size_t)row * DD + d] = p.q;
    } else {
        int blk2 = blk - 2560;                   // [0,512)
        int b = blk2 >> 6;
        int j0 = (blk2 & 63) << 3;
        int jl = tid >> 5, sub = tid & 31;       // 8 j's x 32 workers x 16 i's
        for (int i = tid; i < NN; i += 256) {
            float2 p = ((const float2*)positions)[b * NN + i];
            px[i] = p.x; py[i] = p.y;
        }
        __syncthreads();
        int j = j0 + jl;
        float xj = px[j], yj = py[j];
        union { unsigned char u8[16]; uint4 v; } codes;
#pragma unroll
        for (int t = 0; t < 16; t++) {
            int i = sub * 16 + t;
            int r = rel_of(xj - px[i], yj - py[i]);
            r = (i == j) ? 6 : r;
            codes.u8[t] = (unsigned char)r;
        }
        *(uint4*)&rel[((size_t)(b * NN + j)) * NN + sub * 16] = codes.v;
    }
}

// ----------------------------------------------------------------- gemmT --
// TT[b][e][r*512+i] = sum_d relW[r][d][e]*s0[b][i][d] + relb[r][e]
// LDS-free, barrier-free: fragments loaded directly from L2 (row-major in K).
// Grid (8 it, 24 rm, 8 b) = 1536 blocks = 6/CU.
__global__ __launch_bounds__(256) void gemmT_kernel(
    const ushort* __restrict__ WcT, const ushort* __restrict__ s0b,
    const float* __restrict__ relb, ushort* __restrict__ TT)
{
    int tid = threadIdx.x;
    int b = blockIdx.z;
    int rowM0 = blockIdx.y * 64;           // in [0,1536): r*256+e
    int col0 = blockIdx.x * 64;            // i tile
    int r = rowM0 >> 8, e0 = rowM0 & 255;
    WAVE_IDS();
    ACC_INIT();
    const ushort* gA0 = WcT + (size_t)(e0 + wm * 32 + l15) * 1536 + r * 256 + quad * 8;
    const ushort* gA1 = gA0 + 16 * 1536;
    const ushort* gB0 = s0b + ((size_t)(b * NN) + col0 + wn * 32 + l15) * DD + quad * 8;
    const ushort* gB1 = gB0 + 16 * DD;
#pragma unroll
    for (int s = 0; s < 8; s++) {
        short8 a0 = *(const short8*)(gA0 + s * 32);
        short8 a1 = *(const short8*)(gA1 + s * 32);
        short8 b0 = *(const short8*)(gB0 + s * 32);
        short8 b1 = *(const short8*)(gB1 + s * 32);
        MFMA4(a0, a1, b0, b1);
    }
#pragma unroll
    for (int mt = 0; mt < 2; mt++)
#pragma unroll
        for (int nt = 0; nt < 2; nt++)
#pragma unroll
            for (int v = 0; v < 4; v++) {
                int e = e0 + wm * 32 + mt * 16 + quad * 4 + v;
                int i = col0 + wn * 32 + nt * 16 + l15;
                TT[((size_t)(b * DD) + e) * 3072 + r * 512 + i] =
                    f2bf(acc[mt][nt][v] + relb[r * DD + e]);
            }
}

// ------------------------------------------------------------- agg gemm ---
// symOut[b*512+j][e] += sum_{r,i} 1[rel(j,i)=r] * TT[b][e][r*512+i]
// One-hot A built IN-REGISTER from u8 codes (no A staging); B fragments
// loaded directly from L2-resident TT. No LDS, no barriers.
// 3 K-slices (r-pairs, K=1024), grid (4,8,24) = 768 blocks = 3/CU;
// atomicAdd into symOut (= s0 base from front).
__global__ __launch_bounds__(256) void agg_gemm(
    const unsigned char* __restrict__ rel, const ushort* __restrict__ TT,
    float* __restrict__ symOut)
{
    int tid = threadIdx.x;
    int z = blockIdx.z;
    int b = z / 3, rg = z - b * 3;
    int row0 = blockIdx.y * 64, col0 = blockIdx.x * 64;
    WAVE_IDS();
    ACC_INIT();
    const unsigned char* gC0 = rel + ((size_t)(b * NN) + row0 + wm * 32 + l15) * NN + quad * 8;
    const unsigned char* gC1 = gC0 + 16 * NN;
    const ushort* gB0 = TT + ((size_t)(b * DD) + col0 + wn * 32 + l15) * 3072
                        + rg * 1024 + quad * 8;
    const ushort* gB1 = gB0 + 16 * 3072;
#pragma unroll 8
    for (int s = 0; s < 32; s++) {
        unsigned rr = 2u * rg + (unsigned)(s >> 4);
        int io = (s & 15) * 32;
        uint2 c0 = *(const uint2*)(gC0 + io);
        uint2 c1 = *(const uint2*)(gC1 + io);
        short8 a0 = onehot8(c0, rr);
        short8 a1 = onehot8(c1, rr);
        short8 b0 = *(const short8*)(gB0 + s * 32);
        short8 b1 = *(const short8*)(gB1 + s * 32);
        MFMA4(a0, a1, b0, b1);
    }
#pragma unroll
    for (int mt = 0; mt < 2; mt++)
#pragma unroll
        for (int nt = 0; nt < 2; nt++)
#pragma unroll
            for (int v = 0; v < 4; v++) {
                int j = row0 + wm * 32 + mt * 16 + quad * 4 + v;
                int e = col0 + wn * 32 + nt * 16 + l15;
                atomicAdd(&symOut[((size_t)(b * NN) + j) * DD + e], acc[mt][nt][v]);
            }
}

// ----------------------------------------------------------------- gemm2 --
// symOut(fp32 -> bf16 in-register) @ Wbig^T. Col tiles <768: gelu + fused
// interp reduce (atomicAdd into outI pre-loaded with h2b). Else: out0.
// LDS-free, barrier-free. Grid (16,64) = 1024 blocks = 4/CU.
__global__ __launch_bounds__(256) void gemm2_kernel(
    const float* __restrict__ symOut, const ushort* __restrict__ WbT,
    const float* __restrict__ bbig, const float* __restrict__ h2W,
    float* __restrict__ out0, float* __restrict__ outI)
{
    int tid = threadIdx.x;
    int row0 = blockIdx.y * 64, col0 = blockIdx.x * 64;
    WAVE_IDS();
    ACC_INIT();
    const float*  gA0 = symOut + (size_t)(row0 + wm * 32 + l15) * DD + quad * 8;
    const float*  gA1 = gA0 + 16 * DD;
    const ushort* gB0 = WbT + (size_t)(col0 + wn * 32 + l15) * DD + quad * 8;
    const ushort* gB1 = gB0 + 16 * DD;
#pragma unroll
    for (int s = 0; s < 8; s++) {
        float4 x0 = *(const float4*)(gA0 + s * 32);
        float4 y0 = *(const float4*)(gA0 + s * 32 + 4);
        float4 x1 = *(const float4*)(gA1 + s * 32);
        float4 y1 = *(const float4*)(gA1 + s * 32 + 4);
        short8 a0 = pack_bf8(x0, y0);
        short8 a1 = pack_bf8(x1, y1);
        short8 b0 = *(const short8*)(gB0 + s * 32);
        short8 b1 = *(const short8*)(gB1 + s * 32);
        MFMA4(a0, a1, b0, b1);
    }
    if (col0 >= 768) {
#pragma unroll
        for (int nt = 0; nt < 2; nt++) {
            int c = col0 + wn * 32 + nt * 16 + l15;
            float bb = bbig[c];
#pragma unroll
            for (int mt = 0; mt < 2; mt++)
#pragma unroll
                for (int v = 0; v < 4; v++) {
                    int row = row0 + wm * 32 + mt * 16 + quad * 4 + v;
                    out0[(size_t)row * DD + (c - 768)] = acc[mt][nt][v] + bb;
                }
        }
    } else {
        int head = col0 >> 8;
        float part[2][4];
#pragma unroll
        for (int mt = 0; mt < 2; mt++)
#pragma unroll
            for (int v = 0; v < 4; v++) part[mt][v] = 0.f;
#pragma unroll
        for (int nt = 0; nt < 2; nt++) {
            int c = col0 + wn * 32 + nt * 16 + l15;
            float bb = bbig[c];
            float w2 = h2W[c];
#pragma unroll
            for (int mt = 0; mt < 2; mt++)
#pragma unroll
                for (int v = 0; v < 4; v++)
                    part[mt][v] += gelu_exact(acc[mt][nt][v] + bb) * w2;
        }
#pragma unroll
        for (int mt = 0; mt < 2; mt++)
#pragma unroll
            for (int v = 0; v < 4; v++) {
                float p = part[mt][v];
                p += __shfl_xor(p, 1); p += __shfl_xor(p, 2);
                p += __shfl_xor(p, 4); p += __shfl_xor(p, 8);
                if (l15 == 0) {
                    int row = row0 + wm * 32 + mt * 16 + quad * 4 + v;
                    atomicAdd(&outI[head * BNT + row], p);
                }
            }
    }
}

// ---------------------------------------------------------------- launch --
extern "C" void kernel_launch(void* const* d_in, const int* in_sizes, int n_in,
                              void* d_out, int out_size, void* d_ws, size_t ws_size,
                              hipStream_t stream)
{
    const int*   ids  = (const int*)d_in[0];
    const float* pos  = (const float*)d_in[1];
    const float* symt = (const float*)d_in[2];
    const float* layt = (const float*)d_in[3];
    const float* relW = (const float*)d_in[4];
    const float* relb = (const float*)d_in[5];
    const float* h1W  = (const float*)d_in[6];
    const float* h1b  = (const float*)d_in[7];
    const float* h2W  = (const float*)d_in[8];
    const float* h2b  = (const float*)d_in[9];
    const float* outW = (const float*)d_in[10];
    const float* outb = (const float*)d_in[11];
    float* out = (float*)d_out;
    float* ws  = (float*)d_ws;

    ushort* s0b  = (ushort*)(ws + OFF_S0B);
    ushort* TT   = (ushort*)(ws + OFF_TT);
    ushort* WcT  = (ushort*)(ws + OFF_WCT);
    ushort* WbT  = (ushort*)(ws + OFF_WBT);
    float*  bbig = ws + OFF_BB;
    unsigned char* rel = (unsigned char*)(ws + OFF_REL);

    front_kernel<<<3072, 256, 0, stream>>>(ids, pos, symt, layt, relW, h1W, outW,
                                           h1b, outb, h2b, WcT, WbT, bbig,
                                           out + INTERP_OFF, out + SYM_OFF, s0b, rel);
    gemmT_kernel<<<dim3(8, 24, 8), 256, 0, stream>>>(WcT, s0b, relb, TT);
    agg_gemm<<<dim3(4, 8, 24), 256, 0, stream>>>(rel, TT, out + SYM_OFF);
    gemm2_kernel<<<dim3(16, 64), 256, 0, stream>>>(out + SYM_OFF, WbT,
                                                   bbig, h2W,
                                                   out + OUT0_OFF, out + INTERP_OFF);
}

// Round 3
// 157.726 us; speedup vs baseline: 1.1806x; 1.1806x over previous
//
#include <hip/hip_runtime.h>
#include <hip/hip_bf16.h>
#include <math.h>

#define BB 8
#define NN 512
#define DD 256
#define BNT 4096   // B*N

typedef __attribute__((ext_vector_type(8))) short short8;
typedef __attribute__((ext_vector_type(4))) float f32x4;

// Workspace layout (float offsets). ~18 MB.
#define OFF_S0B   0u          // bf16 [4096][256]      s0 row-major
#define OFF_TT    524288u     // bf16 [8][256][3072]   TT[b][e][r*512+i] = T_r[i][e]+relb_r[e]
#define OFF_WCT   6815744u    // bf16 [256][1536]      WcT[e][r*256+d] = relW[r][d][e]
#define OFF_WBT   7012352u    // bf16 [1024][256]      Wbig^T (c rows, k=d)
#define OFF_BB    7143424u    // fp32 [1024]           h1b|outb
#define OFF_REL   7144448u    // u8   [8][512][512]    relation codes (self=6)

// d_out layout (floats)
#define OUT0_OFF   0u        // output  [8][512][256]
#define INTERP_OFF 1048576u  // interp  [3][4096]
#define SYM_OFF    1060864u  // symbols [8][512][256]

__device__ __forceinline__ float gelu_exact(float x) {
    return 0.5f * x * (1.0f + erff(x * 0.70710678118654752f));
}

__device__ __forceinline__ ushort f2bf(float x) {
    __hip_bfloat16 h = __float2bfloat16(x);
    union { __hip_bfloat16 b; ushort u; } cv;
    cv.b = h;
    return cv.u;
}

// Async global->LDS DMA, 16B per lane. LDS dest is wave-uniform base +
// lane*16; global src is per-lane.
typedef __attribute__((address_space(3))) unsigned int  lds_u32;
typedef __attribute__((address_space(1))) unsigned int  glb_u32;
__device__ __forceinline__ void gload16(const void* g, void* l) {
    __builtin_amdgcn_global_load_lds((const glb_u32*)g, (lds_u32*)l, 16, 0, 0);
}

// Branch-free classification (reference if/elif priority, applied in reverse).
__device__ __forceinline__ int rel_of(float dx, float dy) {
    int r = (fabsf(dx) < 0.3f && fabsf(dy) < 0.3f) ? 4 : 5;
    r = (dx >  0.5f) ? 3 : r;
    r = (dx < -0.5f) ? 2 : r;
    r = (dy < -0.5f) ? 1 : r;
    r = (dy >  0.5f) ? 0 : r;
    return r;
}

// One-hot bf16 fragment from 8 relation-code bytes: 1.0 where code==rr.
__device__ __forceinline__ short8 onehot8(uint2 cw, unsigned rr) {
    union { ushort u[8]; short8 v; } o;
    unsigned m = rr * 0x01010101u;
    unsigned x = cw.x ^ m, y = cw.y ^ m;
#pragma unroll
    for (int t = 0; t < 4; t++) {
        o.u[t]     = (((x >> (8 * t)) & 255u) == 0u) ? 0x3F80 : 0;
        o.u[t + 4] = (((y >> (8 * t)) & 255u) == 0u) ? 0x3F80 : 0;
    }
    return o.v;
}

// 64x64 tile, 4 waves (2x2). Fragment layout (m89/m91 verified):
// A: m=lane&15, k=quad*8+j; B: n=lane&15, k=quad*8+j;
// C/D: col=lane&15, row=quad*4+reg.
// LDS cell layout [k-octet][row] (16B cells) -> conflict-free b128 reads,
// and lane-linear for global_load_lds (wave w stages octet w, lane = row).
#define WAVE_IDS()                                             \
    const int lane = tid & 63, w = tid >> 6;                   \
    const int wm = w >> 1, wn = w & 1;                         \
    const int quad = lane >> 4, l15 = lane & 15;               \
    const int sm = tid >> 2, sq = tid & 3;                     \
    (void)sm; (void)sq;

#define ACC_INIT()                                             \
    f32x4 acc[2][2];                                           \
    _Pragma("unroll") for (int mt = 0; mt < 2; mt++)           \
    _Pragma("unroll") for (int nt = 0; nt < 2; nt++)           \
        acc[mt][nt] = (f32x4){0.f, 0.f, 0.f, 0.f};

#define MFMA4(a0, a1, b0, b1)                                                     \
    acc[0][0] = __builtin_amdgcn_mfma_f32_16x16x32_bf16(a0, b0, acc[0][0], 0, 0, 0); \
    acc[0][1] = __builtin_amdgcn_mfma_f32_16x16x32_bf16(a0, b1, acc[0][1], 0, 0, 0); \
    acc[1][0] = __builtin_amdgcn_mfma_f32_16x16x32_bf16(a1, b0, acc[1][0], 0, 0, 0); \
    acc[1][1] = __builtin_amdgcn_mfma_f32_16x16x32_bf16(a1, b1, acc[1][1], 0, 0, 0);

#define MFMA_STEP(Abuf, Bbuf)                                                \
    {                                                                        \
        short8 af[2], bfr[2];                                                \
        _Pragma("unroll")                                                    \
        for (int mt = 0; mt < 2; mt++)                                       \
            af[mt] = *(const short8*)&(Abuf)[(quad * 64 + wm * 32 + mt * 16 + l15) * 8]; \
        _Pragma("unroll")                                                    \
        for (int nt = 0; nt < 2; nt++)                                       \
            bfr[nt] = *(const short8*)&(Bbuf)[(quad * 64 + wn * 32 + nt * 16 + l15) * 8]; \
        MFMA4(af[0], af[1], bfr[0], bfr[1]);                                 \
    }

// ---------------------------------------------------------------- front ---
// Fused prep (blocks 0..1535) + gather (1536..2559, 4 rows/block, float4)
// + classify (2560..3071).
__global__ __launch_bounds__(256) void front_kernel(
    const int* __restrict__ ids, const float* __restrict__ positions,
    const float* __restrict__ symt, const float* __restrict__ layt,
    const float* __restrict__ relW, const float* __restrict__ h1W,
    const float* __restrict__ outW, const float* __restrict__ h1b,
    const float* __restrict__ outb, const float* __restrict__ h2b,
    ushort* __restrict__ WcT, ushort* __restrict__ WbT,
    float* __restrict__ bbig, float* __restrict__ outI,
    float* __restrict__ symOut, ushort* __restrict__ s0b,
    unsigned char* __restrict__ rel)
{
    __shared__ float px[NN], py[NN];
    int blk = blockIdx.x, tid = threadIdx.x;
    if (blk < 1536) {
        int idx = blk * 256 + tid;               // 393216
        {
            int e = idx / 1536, k = idx - e * 1536;
            int r = k >> 8, d = k & 255;
            WcT[idx] = f2bf(relW[(r * DD + d) * DD + e]);
        }
        if (idx < 262144) {
            int c = idx >> 8, d = idx & 255;
            float v;
            if (c < 768) { int r = c >> 8, e = c & 255; v = h1W[(r * DD + d) * DD + e]; }
            else         { v = outW[d * DD + (c - 768)]; }
            WbT[idx] = f2bf(v);
        }
        if (idx < 3 * BNT) outI[idx] = h2b[idx >> 12];
        if (idx < 1024) bbig[idx] = (idx < 768) ? h1b[idx] : outb[idx - 768];
    } else if (blk < 2560) {
        int row = (blk - 1536) * 4 + (tid >> 6); // 4 rows/block
        int d = (tid & 63) * 4;
        int id = ids[row];
        float4 a = *(const float4*)&symt[(size_t)id * DD + d];
        float4 c = *(const float4*)&layt[(size_t)id * DD + d];
        float4 v = {a.x + c.x, a.y + c.y, a.z + c.z, a.w + c.w};
        *(float4*)&symOut[(size_t)row * DD + d] = v;
        union { ushort u[4]; uint2 q; } p;
        p.u[0] = f2bf(v.x); p.u[1] = f2bf(v.y); p.u[2] = f2bf(v.z); p.u[3] = f2bf(v.w);
        *(uint2*)&s0b[(size_t)row * DD + d] = p.q;
    } else {
        int blk2 = blk - 2560;                   // [0,512)
        int b = blk2 >> 6;
        int j0 = (blk2 & 63) << 3;
        int jl = tid >> 5, sub = tid & 31;       // 8 j's x 32 workers x 16 i's
        for (int i = tid; i < NN; i += 256) {
            float2 p = ((const float2*)positions)[b * NN + i];
            px[i] = p.x; py[i] = p.y;
        }
        __syncthreads();
        int j = j0 + jl;
        float xj = px[j], yj = py[j];
        union { unsigned char u8[16]; uint4 v; } codes;
#pragma unroll
        for (int t = 0; t < 16; t++) {
            int i = sub * 16 + t;
            int r = rel_of(xj - px[i], yj - py[i]);
            r = (i == j) ? 6 : r;
            codes.u8[t] = (unsigned char)r;
        }
        *(uint4*)&rel[((size_t)(b * NN + j)) * NN + sub * 16] = codes.v;
    }
}

// ----------------------------------------------------------------- gemmT --
// TT[b][e][r*512+i] = sum_d relW[r][d][e]*s0[b][i][d] + relb[r][e]
// Double-buffered LDS, staged via async global_load_lds (A and B).
// Grid (8 it, 24 rm, 8 b) = 1536 blocks = 6/CU.
__global__ __launch_bounds__(256) void gemmT_kernel(
    const ushort* __restrict__ WcT, const ushort* __restrict__ s0b,
    const float* __restrict__ relb, ushort* __restrict__ TT)
{
    __shared__ ushort Als[2][2048], Bls[2][2048];
    int tid = threadIdx.x;
    int b = blockIdx.z;
    int rowM0 = blockIdx.y * 64;           // in [0,1536): r*256+e
    int col0 = blockIdx.x * 64;            // i tile
    int r = rowM0 >> 8, e0 = rowM0 & 255;
    WAVE_IDS();
    ACC_INIT();
    // wave w stages k-octet w; lane = row
    const ushort* gA = WcT + (size_t)(e0 + lane) * 1536 + r * 256 + w * 8;
    const ushort* gB = s0b + ((size_t)(b * NN) + col0 + lane) * DD + w * 8;

    gload16(gA, &Als[0][w * 512]);
    gload16(gB, &Bls[0][w * 512]);
    __syncthreads();
#pragma unroll
    for (int s = 0; s < 8; s++) {
        if (s < 7) {
            gload16(gA + (s + 1) * 32, &Als[(s + 1) & 1][w * 512]);
            gload16(gB + (s + 1) * 32, &Bls[(s + 1) & 1][w * 512]);
        }
        MFMA_STEP(Als[s & 1], Bls[s & 1]);
        __syncthreads();
    }
#pragma unroll
    for (int mt = 0; mt < 2; mt++)
#pragma unroll
        for (int nt = 0; nt < 2; nt++)
#pragma unroll
            for (int v = 0; v < 4; v++) {
                int e = e0 + wm * 32 + mt * 16 + quad * 4 + v;
                int i = col0 + wn * 32 + nt * 16 + l15;
                TT[((size_t)(b * DD) + e) * 3072 + r * 512 + i] =
                    f2bf(acc[mt][nt][v] + relb[r * DD + e]);
            }
}

// ------------------------------------------------------------- agg gemm ---
// symOut[b*512+j][e] += sum_i 1[rel(j,i)=r] * TT[b][e][r*512+i], per r.
// One-hot A in-register (prefetched code bytes, no LDS); B double-buffered
// via global_load_lds. Grid (4,8,48): z = b*6+r, K=512 -> 6 blocks/CU.
// atomicAdd into symOut (= s0 base from front).
__global__ __launch_bounds__(256) void agg_gemm(
    const unsigned char* __restrict__ rel, const ushort* __restrict__ TT,
    float* __restrict__ symOut)
{
    __shared__ ushort Bls[2][2048];
    int tid = threadIdx.x;
    int z = blockIdx.z;
    int b = z / 6;
    unsigned rr = (unsigned)(z - b * 6);
    int row0 = blockIdx.y * 64, col0 = blockIdx.x * 64;
    WAVE_IDS();
    ACC_INIT();
    const ushort* gB = TT + ((size_t)(b * DD) + col0 + lane) * 3072 + rr * 512 + w * 8;
    const unsigned char* gC0 = rel + ((size_t)(b * NN) + row0 + wm * 32 + l15) * NN + quad * 8;
    const unsigned char* gC1 = gC0 + 16 * NN;

    gload16(gB, &Bls[0][w * 512]);
    uint2 c0 = *(const uint2*)gC0;
    uint2 c1 = *(const uint2*)gC1;
    __syncthreads();
#pragma unroll
    for (int s = 0; s < 16; s++) {
        uint2 n0 = c0, n1 = c1;
        if (s < 15) {
            gload16(gB + (s + 1) * 32, &Bls[(s + 1) & 1][w * 512]);
            n0 = *(const uint2*)(gC0 + (s + 1) * 32);
            n1 = *(const uint2*)(gC1 + (s + 1) * 32);
        }
        short8 a0 = onehot8(c0, rr);
        short8 a1 = onehot8(c1, rr);
        short8 b0 = *(const short8*)&Bls[s & 1][(quad * 64 + wn * 32 + l15) * 8];
        short8 b1 = *(const short8*)&Bls[s & 1][(quad * 64 + wn * 32 + 16 + l15) * 8];
        MFMA4(a0, a1, b0, b1);
        c0 = n0; c1 = n1;
        __syncthreads();
    }
#pragma unroll
    for (int mt = 0; mt < 2; mt++)
#pragma unroll
        for (int nt = 0; nt < 2; nt++)
#pragma unroll
            for (int v = 0; v < 4; v++) {
                int j = row0 + wm * 32 + mt * 16 + quad * 4 + v;
                int e = col0 + wn * 32 + nt * 16 + l15;
                atomicAdd(&symOut[((size_t)(b * NN) + j) * DD + e], acc[mt][nt][v]);
            }
}

// ----------------------------------------------------------------- gemm2 --
// symOut(fp32 -> bf16 reg-staged) @ Wbig^T; B via global_load_lds.
// Col tiles <768: gelu + fused interp reduce (atomicAdd into outI pre-loaded
// with h2b). Else: out0. Grid (16,64) = 1024 blocks = 4/CU.
__global__ __launch_bounds__(256) void gemm2_kernel(
    const float* __restrict__ symOut, const ushort* __restrict__ WbT,
    const float* __restrict__ bbig, const float* __restrict__ h2W,
    float* __restrict__ out0, float* __restrict__ outI)
{
    __shared__ ushort Als[2][2048], Bls[2][2048];
    int tid = threadIdx.x;
    int row0 = blockIdx.y * 64, col0 = blockIdx.x * 64;
    WAVE_IDS();
    ACC_INIT();
    const float*  gA = symOut + (size_t)(row0 + sm) * DD + sq * 8;   // reg-stage A
    const ushort* gB = WbT + (size_t)(col0 + lane) * DD + w * 8;     // DMA B
    const int lo = (sq * 64 + sm) * 8;

#define G2_STAGE(a0, a1, buf)                                       \
    {                                                               \
        union alignas(16) { ushort u[8]; uint4 v; } am;             \
        am.u[0] = f2bf(a0.x); am.u[1] = f2bf(a0.y);                 \
        am.u[2] = f2bf(a0.z); am.u[3] = f2bf(a0.w);                 \
        am.u[4] = f2bf(a1.x); am.u[5] = f2bf(a1.y);                 \
        am.u[6] = f2bf(a1.z); am.u[7] = f2bf(a1.w);                 \
        *(uint4*)&Als[buf][lo] = am.v;                              \
    }

    float4 a0 = *(const float4*)gA;
    float4 a1 = *(const float4*)(gA + 4);
    gload16(gB, &Bls[0][w * 512]);
    G2_STAGE(a0, a1, 0);
    __syncthreads();
#pragma unroll
    for (int s = 0; s < 8; s++) {
        float4 x = a0, y = a1;
        if (s < 7) {
            x = *(const float4*)(gA + (s + 1) * 32);
            y = *(const float4*)(gA + (s + 1) * 32 + 4);
            gload16(gB + (s + 1) * 32, &Bls[(s + 1) & 1][w * 512]);
        }
        MFMA_STEP(Als[s & 1], Bls[s & 1]);
        if (s < 7) { G2_STAGE(x, y, (s + 1) & 1); }
        __syncthreads();
    }
#undef G2_STAGE
    if (col0 >= 768) {
#pragma unroll
        for (int nt = 0; nt < 2; nt++) {
            int c = col0 + wn * 32 + nt * 16 + l15;
            float bb = bbig[c];
#pragma unroll
            for (int mt = 0; mt < 2; mt++)
#pragma unroll
                for (int v = 0; v < 4; v++) {
                    int row = row0 + wm * 32 + mt * 16 + quad * 4 + v;
                    out0[(size_t)row * DD + (c - 768)] = acc[mt][nt][v] + bb;
                }
        }
    } else {
        int head = col0 >> 8;
        float part[2][4];
#pragma unroll
        for (int mt = 0; mt < 2; mt++)
#pragma unroll
            for (int v = 0; v < 4; v++) part[mt][v] = 0.f;
#pragma unroll
        for (int nt = 0; nt < 2; nt++) {
            int c = col0 + wn * 32 + nt * 16 + l15;
            float bb = bbig[c];
            float w2 = h2W[c];
#pragma unroll
            for (int mt = 0; mt < 2; mt++)
#pragma unroll
                for (int v = 0; v < 4; v++)
                    part[mt][v] += gelu_exact(acc[mt][nt][v] + bb) * w2;
        }
#pragma unroll
        for (int mt = 0; mt < 2; mt++)
#pragma unroll
            for (int v = 0; v < 4; v++) {
                float p = part[mt][v];
                p += __shfl_xor(p, 1); p += __shfl_xor(p, 2);
                p += __shfl_xor(p, 4); p += __shfl_xor(p, 8);
                if (l15 == 0) {
                    int row = row0 + wm * 32 + mt * 16 + quad * 4 + v;
                    atomicAdd(&outI[head * BNT + row], p);
                }
            }
    }
}

// ---------------------------------------------------------------- launch --
extern "C" void kernel_launch(void* const* d_in, const int* in_sizes, int n_in,
                              void* d_out, int out_size, void* d_ws, size_t ws_size,
                              hipStream_t stream)
{
    const int*   ids  = (const int*)d_in[0];
    const float* pos  = (const float*)d_in[1];
    const float* symt = (const float*)d_in[2];
    const float* layt = (const float*)d_in[3];
    const float* relW = (const float*)d_in[4];
    const float* relb = (const float*)d_in[5];
    const float* h1W  = (const float*)d_in[6];
    const float* h1b  = (const float*)d_in[7];
    const float* h2W  = (const float*)d_in[8];
    const float* h2b  = (const float*)d_in[9];
    const float* outW = (const float*)d_in[10];
    const float* outb = (const float*)d_in[11];
    float* out = (float*)d_out;
    float* ws  = (float*)d_ws;

    ushort* s0b  = (ushort*)(ws + OFF_S0B);
    ushort* TT   = (ushort*)(ws + OFF_TT);
    ushort* WcT  = (ushort*)(ws + OFF_WCT);
    ushort* WbT  = (ushort*)(ws + OFF_WBT);
    float*  bbig = ws + OFF_BB;
    unsigned char* rel = (unsigned char*)(ws + OFF_REL);

    front_kernel<<<3072, 256, 0, stream>>>(ids, pos, symt, layt, relW, h1W, outW,
                                           h1b, outb, h2b, WcT, WbT, bbig,
                                           out + INTERP_OFF, out + SYM_OFF, s0b, rel);
    gemmT_kernel<<<dim3(8, 24, 8), 256, 0, stream>>>(WcT, s0b, relb, TT);
    agg_gemm<<<dim3(4, 8, 48), 256, 0, stream>>>(rel, TT, out + SYM_OFF);
    gemm2_kernel<<<dim3(16, 64), 256, 0, stream>>>(out + SYM_OFF, WbT,
                                                   bbig, h2W,
                                                   out + OUT0_OFF, out + INTERP_OFF);
}